// Round 17
// baseline (25.711 us; speedup 1.0000x reference)
//
#include <hip/hip_runtime.h>
#include <hip/hip_bf16.h>

namespace {

constexpr int KIN  = 32;    // IN_CH
constexpr int KOUT = 64;    // OUT_CH
constexpr int KW   = 9;     // KERNEL
constexpr int KPAD = 4;     // PADDING
constexpr int LIN  = 2048;
constexpr int KTOT = 2592;  // 9 taps * 288 features

typedef __bf16 bf16x8 __attribute__((ext_vector_type(8)));
typedef float  f32x4  __attribute__((ext_vector_type(4)));
typedef float  f32x16 __attribute__((ext_vector_type(16)));
typedef unsigned short u16x4 __attribute__((ext_vector_type(4)));
typedef unsigned short u16x8 __attribute__((ext_vector_type(8)));

__device__ __forceinline__ unsigned short f2bf(float x) {
    unsigned int u = __float_as_uint(x);
    u += 0x7FFFu + ((u >> 16) & 1u);   // RNE
    return (unsigned short)(u >> 16);
}

__device__ __forceinline__ float bf2f(unsigned short h) {
    return __uint_as_float((unsigned int)h << 16);
}

#define MFMA32(a, b, c) __builtin_amdgcn_mfma_f32_32x32x16_bf16((a), (b), (c), 0, 0, 0)

// ---- kernel 1: weights -> 32x32x16 MFMA-fragment order, output-coalesced ----
// Slot idx=(ch,mb,l): ch=K-chunk of 16 (0..161), mb=o-block of 32, l=lane.
// Element e: o = mb*32 + (l&31), kappa = ch*16 + (l>>5)*8 + e.
__global__ __launch_bounds__(256) void kan_wprep(const float* __restrict__ base_w,
                                                 const float* __restrict__ spline_w,
                                                 const float* __restrict__ spline_scaler,
                                                 unsigned short* __restrict__ Wf) {
    unsigned int idx = blockIdx.x * 256 + threadIdx.x;    // < 162*2*64 = 20736
    unsigned int ch  = idx >> 7;          // 0..161
    unsigned int mb  = (idx >> 6) & 1;
    unsigned int l   = idx & 63;
    unsigned int o   = mb * 32 + (l & 31);
    unsigned int kb  = ch * 16 + (l >> 5) * 8;

    u16x8 pk;
#pragma unroll
    for (int e = 0; e < 8; ++e) {
        unsigned int kappa = kb + e;
        unsigned int k  = kappa / 288;        // conv tap
        unsigned int r2 = kappa - k * 288;
        unsigned int i  = r2 / 9;             // in-channel
        unsigned int c  = r2 - i * 9;         // 0 = silu, 1..8 = spline coef
        unsigned int t  = o * 288 + i * 9 + k;
        float val = (c == 0) ? base_w[t]
                             : spline_w[(size_t)t * 8 + (c - 1)] * spline_scaler[t];
        pk[e] = f2bf(val);
    }
    *(u16x8*)(Wf + (size_t)idx * 8) = pk;
}

// ---- kernel 2: fused features + 8-way split-K, 32x32x16 MFMA ----
constexpr int BN     = 64;
constexpr int TROW   = 72;    // BN + KW - 1
constexpr int F2COLS = 296;   // 592B rows; 32-row b128 reads spread uniformly

__global__ __launch_bounds__(512, 4) void kan_fused(const float* __restrict__ x,
                                                    const unsigned short* __restrict__ Wf,
                                                    float* __restrict__ out) {
    __shared__ __align__(16) char smem[TROW * F2COLS * 2];   // 42624B; red16 aliases 32KB
    unsigned short* f2t = (unsigned short*)smem;

    int tid  = threadIdx.x;
    int lane = tid & 63;
    int wv   = tid >> 6;          // 0..7
    int l31  = lane & 31;
    int hi2  = lane >> 5;         // 0..1

    int blk = blockIdx.x;
    int b   = blk >> 5;
    int l0  = (blk & 31) * BN;

    // ---- split-K geometry + prime-A hoist ----
    const int ch0 = 20 * wv;      // wave owns chunks [ch0, ch0+20) of 0..159
    constexpr int NCHW = 20;
    int kk = ch0 / 18;
    int jb = ch0 - kk * 18;       // 16-j units within tap
    const unsigned short* wp = Wf + (size_t)ch0 * 1024 + (size_t)lane * 8;
    bf16x8 a0 = *(const bf16x8*)(wp);          // mb=0
    bf16x8 a1 = *(const bf16x8*)(wp + 512);    // mb=1

    // ---- hoist x loads (long latency) ahead of LDS zeroing ----
    float vv[5];
#pragma unroll
    for (int p = 0; p < 5; ++p) {
        int unit = p * 512 + tid;
        bool ok = unit < TROW * KIN;
        int i = unit / TROW;
        int r = unit - i * TROW;
        int gx = l0 + r - KPAD;
        vv[p] = 0.f;
        if (ok && gx >= 0 && gx < LIN) vv[p] = x[((size_t)b * KIN + i) * LIN + gx];
    }

    // ---- zero f2t (2664 x 16B) ----
    {
        f32x4 z = (f32x4){0.f, 0.f, 0.f, 0.f};
        for (int c = tid; c < TROW * F2COLS / 8; c += 512)
            *(f32x4*)(f2t + (size_t)c * 8) = z;
    }
    __syncthreads();

    // ---- features: silu + closed-form cubic B-spline, scatter to LDS ----
#pragma unroll
    for (int p = 0; p < 5; ++p) {
        int unit = p * 512 + tid;
        bool ok = unit < TROW * KIN;
        int i = unit / TROW;
        int r = unit - i * TROW;
        float v = vv[p];
        if (ok) {
            unsigned short* row = f2t + (size_t)r * F2COLS + i * 9;
            row[0] = f2bf(v / (1.f + __expf(-v)));             // silu
            float t5 = (v + 2.2f) * 2.5f;                       // knots at -2.2 + 0.4*j
            float mf = floorf(t5);
            int   m  = (int)mf;
            float u  = t5 - mf;
            float u2 = u * u, u3 = u2 * u;
            float w  = 1.f - u;
            float P0 = u3 * (1.f / 6.f);
            float P3 = w * w * w * (1.f / 6.f);
            float P1 = (1.f / 6.f) + 0.5f * u + 0.5f * u2 - 0.5f * u3;
            float P2 = (4.f / 6.f) - u2 + 0.5f * u3;
            int c0 = m - 3;
            if ((unsigned)(c0 + 0) <= 7u) row[1 + c0 + 0] = f2bf(P3);
            if ((unsigned)(c0 + 1) <= 7u) row[1 + c0 + 1] = f2bf(P2);
            if ((unsigned)(c0 + 2) <= 7u) row[1 + c0 + 2] = f2bf(P1);
            if ((unsigned)(c0 + 3) <= 7u) row[1 + c0 + 3] = f2bf(P0);
        }
    }
    __syncthreads();

    // ---- K-loop: 20 chunks of K=16; 4 MFMA (2 mb x 2 nb) per chunk ----
    f32x16 acc00 = {}, acc01 = {}, acc10 = {}, acc11 = {};

    // B frag: lane -> n = nb*32 + l31, kappa = ch*16 + hi2*8 + e
    const unsigned short* fp = f2t + (size_t)(l31 + kk) * F2COLS + jb * 16 + hi2 * 8;
    bf16x8 b0 = *(const bf16x8*)(fp);                    // nb=0
    bf16x8 b1 = *(const bf16x8*)(fp + 32 * F2COLS);      // nb=1

    for (int t = 0; t < NCHW; ++t) {
        bool last = (t + 1 == NCHW);
        const unsigned short* wpn = last ? wp : wp + 1024;
        int jb2 = last ? jb : jb + 1;
        const unsigned short* fpn = last ? fp : fp + ((jb2 == 18) ? 24 : 16);
        if (jb2 == 18) jb2 = 0;    // wrap: next tap row (+F2COLS), col reset (-272)

        // prefetch A(t+1): MFMA block below hides L2 latency
        bf16x8 na0 = *(const bf16x8*)(wpn);
        bf16x8 na1 = *(const bf16x8*)(wpn + 512);

        __builtin_amdgcn_s_setprio(1);
        acc00 = MFMA32(a0, b0, acc00);
        acc10 = MFMA32(a1, b0, acc10);
        b0 = *(const bf16x8*)(fpn);
        acc01 = MFMA32(a0, b1, acc01);
        acc11 = MFMA32(a1, b1, acc11);
        b1 = *(const bf16x8*)(fpn + 32 * F2COLS);
        __builtin_amdgcn_s_setprio(0);

        a0 = na0; a1 = na1;
        wp = wpn; fp = fpn; jb = jb2;
    }

    // ---- balanced tail: chunks 160,161 (tap 8, jb 16,17): 1 MFMA per wave ----
    {
        int chT = 160 + (wv >> 2);            // 160 for wv 0-3, 161 for wv 4-7
        int jbT = 16 + (wv >> 2);
        int mbT = (wv >> 1) & 1;
        int nbT = wv & 1;
        bf16x8 aT = *(const bf16x8*)(Wf + ((size_t)chT * 2 + mbT) * 512 + (size_t)lane * 8);
        bf16x8 bT = *(const bf16x8*)(f2t + (size_t)(nbT * 32 + l31 + 8) * F2COLS + jbT * 16 + hi2 * 8);
        switch (wv) {   // wave-uniform branch; static acc names
        case 0: acc00 = MFMA32(aT, bT, acc00); break;
        case 1: acc01 = MFMA32(aT, bT, acc01); break;
        case 2: acc10 = MFMA32(aT, bT, acc10); break;
        case 3: acc11 = MFMA32(aT, bT, acc11); break;
        case 4: acc00 = MFMA32(aT, bT, acc00); break;
        case 5: acc01 = MFMA32(aT, bT, acc01); break;
        case 6: acc10 = MFMA32(aT, bT, acc10); break;
        case 7: acc11 = MFMA32(aT, bT, acc11); break;
        }
    }

    // ---- reduction: two phases over mb; bf16 partials, 32KB each ----
    // D layout (verified m74/m101): col = lane&31, row = (reg&3) + 8*(reg>>2) + 4*(lane>>5)
    __syncthreads();   // all waves done reading f2t
    unsigned short* red16 = (unsigned short*)smem;
#pragma unroll
    for (int mp = 0; mp < 2; ++mp) {
        f32x16 wA = (mp == 0) ? acc00 : acc10;   // nb=0
        f32x16 wB = (mp == 0) ? acc01 : acc11;   // nb=1
        {
            unsigned short* s0 = red16 + (((size_t)(0 * 8 + wv)) * 64 + lane) * 16;
            unsigned short* s1 = red16 + (((size_t)(1 * 8 + wv)) * 64 + lane) * 16;
#pragma unroll
            for (int g = 0; g < 4; ++g) {
                u16x4 pA = (u16x4){f2bf(wA[g * 4 + 0]), f2bf(wA[g * 4 + 1]),
                                   f2bf(wA[g * 4 + 2]), f2bf(wA[g * 4 + 3])};
                u16x4 pB = (u16x4){f2bf(wB[g * 4 + 0]), f2bf(wB[g * 4 + 1]),
                                   f2bf(wB[g * 4 + 2]), f2bf(wB[g * 4 + 3])};
                *(u16x4*)(s0 + g * 4) = pA;
                *(u16x4*)(s1 + g * 4) = pB;
            }
        }
        __syncthreads();
        {
            int nb = wv & 1;          // subtile column half
            int q  = wv >> 1;         // reg-quad 0..3
            f32x4 s = (f32x4){0.f, 0.f, 0.f, 0.f};
#pragma unroll
            for (int w = 0; w < 8; ++w) {
                u16x4 pk = *(const u16x4*)(red16 + (((size_t)(nb * 8 + w)) * 64 + lane) * 16 + q * 4);
                s[0] += bf2f(pk[0]);
                s[1] += bf2f(pk[1]);
                s[2] += bf2f(pk[2]);
                s[3] += bf2f(pk[3]);
            }
            // reg = q*4 + r  ->  o = mp*32 + r + 8*q + 4*hi2
            int o = mp * 32 + 8 * q + 4 * hi2;
            float* op = out + ((size_t)b * KOUT + o) * LIN + l0 + nb * 32 + l31;
            op[0]               = s[0];
            op[LIN]             = s[1];
            op[2 * LIN]         = s[2];
            op[3 * (size_t)LIN] = s[3];
        }
        if (mp == 0) __syncthreads();
    }
}

} // namespace

extern "C" void kernel_launch(void* const* d_in, const int* in_sizes, int n_in,
                              void* d_out, int out_size, void* d_ws, size_t ws_size,
                              hipStream_t stream) {
    const float* x             = (const float*)d_in[0];
    const float* base_w        = (const float*)d_in[1];
    const float* spline_w      = (const float*)d_in[2];
    const float* spline_scaler = (const float*)d_in[3];
    float* out = (float*)d_out;

    unsigned short* Wf = (unsigned short*)d_ws;   // 162*2*64*8 u16 = 331776 B

    kan_wprep<<<81, 256, 0, stream>>>(base_w, spline_w, spline_scaler, Wf);
    kan_fused<<<512, 512, 0, stream>>>(x, Wf, out);
}

// Round 18
// 22.843 us; speedup vs baseline: 1.1256x; 1.1256x over previous
//
#include <hip/hip_runtime.h>
#include <hip/hip_bf16.h>

namespace {

constexpr int KIN  = 32;    // IN_CH
constexpr int KOUT = 64;    // OUT_CH
constexpr int KW   = 9;     // KERNEL
constexpr int KPAD = 4;     // PADDING
constexpr int LIN  = 2048;
constexpr int KTOT = 2592;  // 9 taps * 288 features

typedef __bf16 bf16x8 __attribute__((ext_vector_type(8)));
typedef float  f32x4  __attribute__((ext_vector_type(4)));
typedef unsigned short u16x4 __attribute__((ext_vector_type(4)));
typedef unsigned short u16x8 __attribute__((ext_vector_type(8)));

__device__ __forceinline__ unsigned short f2bf(float x) {
    unsigned int u = __float_as_uint(x);
    u += 0x7FFFu + ((u >> 16) & 1u);   // RNE
    return (unsigned short)(u >> 16);
}

__device__ __forceinline__ float bf2f(unsigned short h) {
    return __uint_as_float((unsigned int)h << 16);
}

#define MFMA16(a, b, c) __builtin_amdgcn_mfma_f32_16x16x32_bf16((a), (b), (c), 0, 0, 0)

// ---- kernel 1: weights -> MFMA-fragment order, output-coalesced (R12) ----
// Thread owns one 16B slot: idx=(ch,m,lane); writes Wf[idx*8 .. idx*8+7]
// where element e has kappa = ch*32 + (lane>>4)*8 + e, o = m*16 + (lane&15).
__global__ __launch_bounds__(256) void kan_wprep(const float* __restrict__ base_w,
                                                 const float* __restrict__ spline_w,
                                                 const float* __restrict__ spline_scaler,
                                                 unsigned short* __restrict__ Wf) {
    unsigned int idx = blockIdx.x * 256 + threadIdx.x;    // < 81*4*64 = 20736
    unsigned int ch  = idx >> 8;          // 0..80
    unsigned int m   = (idx >> 6) & 3;    // o-block
    unsigned int lane = idx & 63;
    unsigned int o  = m * 16 + (lane & 15);
    unsigned int kb = ch * 32 + (lane >> 4) * 8;   // first kappa of this slot

    u16x8 pk;
#pragma unroll
    for (int e = 0; e < 8; ++e) {
        unsigned int kappa = kb + e;
        unsigned int k  = kappa / 288;        // conv tap
        unsigned int r2 = kappa - k * 288;
        unsigned int i  = r2 / 9;             // in-channel
        unsigned int c  = r2 - i * 9;         // 0 = silu, 1..8 = spline coef
        unsigned int t  = o * 288 + i * 9 + k;
        float val = (c == 0) ? base_w[t]
                             : spline_w[(size_t)t * 8 + (c - 1)] * spline_scaler[t];
        pk[e] = f2bf(val);
    }
    *(u16x8*)(Wf + (size_t)idx * 8) = pk;
}

// ---- kernel 2: fused features + barrier-free 8-way split-K, balanced ----
constexpr int BN     = 64;
constexpr int TROW   = 72;    // BN + KW - 1
constexpr int F2COLS = 296;   // 592B rows; b128 reads spread 2-way max (free)

__global__ __launch_bounds__(512, 4) void kan_fused(const float* __restrict__ x,
                                                    const unsigned short* __restrict__ Wf,
                                                    float* __restrict__ out) {
    __shared__ __align__(16) char smem[65536];   // f2t 42624B / red16 64KB (aliased)
    unsigned short* f2t = (unsigned short*)smem;

    int tid  = threadIdx.x;
    int lane = tid & 63;
    int wv   = tid >> 6;          // 0..7
    int lo = lane & 15, hi = lane >> 4;

    int blk = blockIdx.x;
    int b   = blk >> 5;
    int l0  = (blk & 31) * BN;

    // ---- split-K geometry + prime-A hoist (L2 latency hides under LDS phases) ----
    const int ch0 = 10 * wv;
    constexpr int NCHW = 10;
    int kk = ch0 / 9;
    int jb = ch0 - kk * 9;
    const unsigned short* wp = Wf + (size_t)ch0 * 2048 + (size_t)lane * 8;
    bf16x8 a0 = *(const bf16x8*)(wp);
    bf16x8 a1 = *(const bf16x8*)(wp + 512);
    bf16x8 a2 = *(const bf16x8*)(wp + 1024);
    bf16x8 a3 = *(const bf16x8*)(wp + 1536);

    // ---- hoist x loads (long latency) ahead of LDS zeroing ----
    float vv[5];
#pragma unroll
    for (int p = 0; p < 5; ++p) {
        int unit = p * 512 + tid;
        bool ok = unit < TROW * KIN;
        int i = unit / TROW;
        int r = unit - i * TROW;
        int gx = l0 + r - KPAD;
        vv[p] = 0.f;
        if (ok && gx >= 0 && gx < LIN) vv[p] = x[((size_t)b * KIN + i) * LIN + gx];
    }

    // ---- zero f2t (2664 x 16B) ----
    {
        f32x4 z = (f32x4){0.f, 0.f, 0.f, 0.f};
        for (int c = tid; c < TROW * F2COLS / 8; c += 512)
            *(f32x4*)(f2t + (size_t)c * 8) = z;
    }
    __syncthreads();

    // ---- features: silu + closed-form cubic B-spline, scatter to LDS ----
#pragma unroll
    for (int p = 0; p < 5; ++p) {
        int unit = p * 512 + tid;
        bool ok = unit < TROW * KIN;
        int i = unit / TROW;
        int r = unit - i * TROW;
        float v = vv[p];
        if (ok) {
            unsigned short* row = f2t + (size_t)r * F2COLS + i * 9;
            row[0] = f2bf(v / (1.f + __expf(-v)));             // silu
            float t5 = (v + 2.2f) * 2.5f;                       // knots at -2.2 + 0.4*j
            float mf = floorf(t5);
            int   m  = (int)mf;
            float u  = t5 - mf;
            float u2 = u * u, u3 = u2 * u;
            float w  = 1.f - u;
            float P0 = u3 * (1.f / 6.f);
            float P3 = w * w * w * (1.f / 6.f);
            float P1 = (1.f / 6.f) + 0.5f * u + 0.5f * u2 - 0.5f * u3;
            float P2 = (4.f / 6.f) - u2 + 0.5f * u3;
            int c0 = m - 3;
            if ((unsigned)(c0 + 0) <= 7u) row[1 + c0 + 0] = f2bf(P3);
            if ((unsigned)(c0 + 1) <= 7u) row[1 + c0 + 1] = f2bf(P2);
            if ((unsigned)(c0 + 2) <= 7u) row[1 + c0 + 2] = f2bf(P1);
            if ((unsigned)(c0 + 3) <= 7u) row[1 + c0 + 3] = f2bf(P0);
        }
    }
    __syncthreads();

    // ---- 8-way split-K: wave wv owns chunks [10*wv, 10*wv+10) of 0..79 ----
    f32x4 acc[4][4];
#pragma unroll
    for (int m = 0; m < 4; ++m)
#pragma unroll
        for (int n = 0; n < 4; ++n) acc[m][n] = (f32x4){0.f, 0.f, 0.f, 0.f};

    const unsigned short* fp = f2t + (size_t)(lo + kk) * F2COLS + jb * 32 + hi * 8;
    bf16x8 b0 = *(const bf16x8*)(fp);
    bf16x8 b1 = *(const bf16x8*)(fp + 16 * F2COLS);
    bf16x8 b2 = *(const bf16x8*)(fp + 32 * F2COLS);
    bf16x8 b3 = *(const bf16x8*)(fp + 48 * F2COLS);

    for (int t = 0; t < NCHW; ++t) {
        // next-chunk pointers (clamped on last iteration -> harmless reload)
        bool last = (t + 1 == NCHW);
        const unsigned short* wpn = last ? wp : wp + 2048;
        int jb2 = last ? jb : jb + 1;
        const unsigned short* fpn = last ? fp : fp + ((jb2 == 9) ? (F2COLS - 8 * 32) : 32);
        if (jb2 == 9) jb2 = 0;

        // prefetch A(t+1) early: full MFMA block below hides L2 latency
        bf16x8 na0 = *(const bf16x8*)(wpn);
        bf16x8 na1 = *(const bf16x8*)(wpn + 512);
        bf16x8 na2 = *(const bf16x8*)(wpn + 1024);
        bf16x8 na3 = *(const bf16x8*)(wpn + 1536);

        __builtin_amdgcn_s_setprio(1);
        // n-major: finish consumers of b_n, then reload b_n in place for t+1
        acc[0][0] = MFMA16(a0, b0, acc[0][0]);
        acc[1][0] = MFMA16(a1, b0, acc[1][0]);
        acc[2][0] = MFMA16(a2, b0, acc[2][0]);
        acc[3][0] = MFMA16(a3, b0, acc[3][0]);
        b0 = *(const bf16x8*)(fpn);
        acc[0][1] = MFMA16(a0, b1, acc[0][1]);
        acc[1][1] = MFMA16(a1, b1, acc[1][1]);
        acc[2][1] = MFMA16(a2, b1, acc[2][1]);
        acc[3][1] = MFMA16(a3, b1, acc[3][1]);
        b1 = *(const bf16x8*)(fpn + 16 * F2COLS);
        acc[0][2] = MFMA16(a0, b2, acc[0][2]);
        acc[1][2] = MFMA16(a1, b2, acc[1][2]);
        acc[2][2] = MFMA16(a2, b2, acc[2][2]);
        acc[3][2] = MFMA16(a3, b2, acc[3][2]);
        b2 = *(const bf16x8*)(fpn + 32 * F2COLS);
        acc[0][3] = MFMA16(a0, b3, acc[0][3]);
        acc[1][3] = MFMA16(a1, b3, acc[1][3]);
        acc[2][3] = MFMA16(a2, b3, acc[2][3]);
        acc[3][3] = MFMA16(a3, b3, acc[3][3]);
        b3 = *(const bf16x8*)(fpn + 48 * F2COLS);
        __builtin_amdgcn_s_setprio(0);

        a0 = na0; a1 = na1; a2 = na2; a3 = na3;
        wp = wpn; fp = fpn; jb = jb2;
    }

    // ---- balanced chunk 80 (kappa 2560..2591, tap 8, j-block 8): 2 MFMA/wave ----
    {
        int mq = wv & 3;                  // m-frag this wave covers
        int np = wv >> 2;                 // n-pair (0: n=0,1; 1: n=2,3)
        bf16x8 a80 = *(const bf16x8*)(Wf + (size_t)80 * 2048 + (size_t)mq * 512 + (size_t)lane * 8);
        const unsigned short* fp80 = f2t + (size_t)(lo + 8) * F2COLS + 8 * 32 + hi * 8;
        bf16x8 bA = *(const bf16x8*)(fp80 + (size_t)(2 * np) * 16 * F2COLS);
        bf16x8 bB = *(const bf16x8*)(fp80 + (size_t)(2 * np + 1) * 16 * F2COLS);
        switch (wv) {   // wave-uniform branch; static acc indices (no scratch)
        case 0: acc[0][0] = MFMA16(a80, bA, acc[0][0]); acc[0][1] = MFMA16(a80, bB, acc[0][1]); break;
        case 1: acc[1][0] = MFMA16(a80, bA, acc[1][0]); acc[1][1] = MFMA16(a80, bB, acc[1][1]); break;
        case 2: acc[2][0] = MFMA16(a80, bA, acc[2][0]); acc[2][1] = MFMA16(a80, bB, acc[2][1]); break;
        case 3: acc[3][0] = MFMA16(a80, bA, acc[3][0]); acc[3][1] = MFMA16(a80, bB, acc[3][1]); break;
        case 4: acc[0][2] = MFMA16(a80, bA, acc[0][2]); acc[0][3] = MFMA16(a80, bB, acc[0][3]); break;
        case 5: acc[1][2] = MFMA16(a80, bA, acc[1][2]); acc[1][3] = MFMA16(a80, bB, acc[1][3]); break;
        case 6: acc[2][2] = MFMA16(a80, bA, acc[2][2]); acc[2][3] = MFMA16(a80, bB, acc[2][3]); break;
        case 7: acc[3][2] = MFMA16(a80, bA, acc[3][2]); acc[3][3] = MFMA16(a80, bB, acc[3][3]); break;
        }
    }

    // ---- single-phase 8-way cross-wave reduction, bf16 partials (64KB exact) ----
    __syncthreads();   // all waves done reading f2t
    unsigned short* red16 = (unsigned short*)smem;
#pragma unroll
    for (int m = 0; m < 4; ++m)
#pragma unroll
        for (int n = 0; n < 4; ++n) {
            int sid = m * 4 + n;
            f32x4 a = acc[m][n];
            u16x4 pk = (u16x4){f2bf(a[0]), f2bf(a[1]), f2bf(a[2]), f2bf(a[3])};
            *(u16x4*)(red16 + (((size_t)sid * 8 + wv) * 64 + lane) * 4) = pk;
        }
    __syncthreads();
#pragma unroll
    for (int s = 0; s < 2; ++s) {
        int sid = wv * 2 + s;
        int m = sid >> 2, n = sid & 3;
        f32x4 acc_s = (f32x4){0.f, 0.f, 0.f, 0.f};
#pragma unroll
        for (int w = 0; w < 8; ++w) {
            u16x4 pk = *(const u16x4*)(red16 + (((size_t)sid * 8 + w) * 64 + lane) * 4);
            acc_s[0] += bf2f(pk[0]);
            acc_s[1] += bf2f(pk[1]);
            acc_s[2] += bf2f(pk[2]);
            acc_s[3] += bf2f(pk[3]);
        }
        int o = m * 16 + hi * 4;
        float* op = out + ((size_t)b * KOUT + o) * LIN + l0 + n * 16 + lo;
        op[0]               = acc_s[0];
        op[LIN]             = acc_s[1];
        op[2 * LIN]         = acc_s[2];
        op[3 * (size_t)LIN] = acc_s[3];
    }
}

} // namespace

extern "C" void kernel_launch(void* const* d_in, const int* in_sizes, int n_in,
                              void* d_out, int out_size, void* d_ws, size_t ws_size,
                              hipStream_t stream) {
    const float* x             = (const float*)d_in[0];
    const float* base_w        = (const float*)d_in[1];
    const float* spline_w      = (const float*)d_in[2];
    const float* spline_scaler = (const float*)d_in[3];
    float* out = (float*)d_out;

    unsigned short* Wf = (unsigned short*)d_ws;   // 81*4*64*8 u16 = 331776 B

    kan_wprep<<<81, 256, 0, stream>>>(base_w, spline_w, spline_scaler, Wf);
    kan_fused<<<512, 512, 0, stream>>>(x, Wf, out);
}